// Round 1
// baseline (347.166 us; speedup 1.0000x reference)
//
#include <hip/hip_runtime.h>
#include <hip/hip_bf16.h>

// Problem constants
#define BDIM 4
#define CDIM 2048
#define DDIM 512
#define HH   8
#define DKH  64
#define NROW (BDIM * CDIM)   // 8192

typedef unsigned short u16;
typedef u16   u16x8  __attribute__((ext_vector_type(8)));
typedef __bf16 bf16x8 __attribute__((ext_vector_type(8)));
typedef float f32x4  __attribute__((ext_vector_type(4)));

__device__ __forceinline__ u16 f2bf(float f) {
  union { float f; unsigned u; } x; x.f = f;
  unsigned u = x.u;
  u += 0x7fffu + ((u >> 16) & 1u);   // RNE
  return (u16)(u >> 16);
}

__device__ __forceinline__ void gload_lds16(const u16* gp, u16* lp) {
  // async global->LDS, 16B per lane; LDS dest is wave-uniform base + lane*16
  __builtin_amdgcn_global_load_lds((__attribute__((address_space(1))) const void*)gp,
                                   (__attribute__((address_space(3))) void*)lp, 16, 0, 0);
}

// ---------------- LayerNorm: one wave per row of 512, fp32 in -> bf16 out ---
__global__ __launch_bounds__(256) void ln_kernel(const float* __restrict__ x,
                                                 const float* __restrict__ gamma,
                                                 const float* __restrict__ beta,
                                                 u16* __restrict__ y, int nrows) {
  int gw = (blockIdx.x * 256 + threadIdx.x) >> 6;
  int l  = threadIdx.x & 63;
  if (gw >= nrows) return;
  const float* xr = x + (size_t)gw * DDIM;
  float4 a = *(const float4*)(xr + l * 8);
  float4 b = *(const float4*)(xr + l * 8 + 4);
  float s = a.x + a.y + a.z + a.w + b.x + b.y + b.z + b.w;
  float q = a.x*a.x + a.y*a.y + a.z*a.z + a.w*a.w + b.x*b.x + b.y*b.y + b.z*b.z + b.w*b.w;
#pragma unroll
  for (int m = 1; m < 64; m <<= 1) { s += __shfl_xor(s, m); q += __shfl_xor(q, m); }
  float mu  = s * (1.0f / DDIM);
  float var = q * (1.0f / DDIM) - mu * mu;
  float rs  = rsqrtf(var + 1e-5f);
  float4 g0 = *(const float4*)(gamma + l * 8);
  float4 g1 = *(const float4*)(gamma + l * 8 + 4);
  float4 b0 = *(const float4*)(beta + l * 8);
  float4 b1 = *(const float4*)(beta + l * 8 + 4);
  u16x8 o;
  o[0] = f2bf((a.x - mu) * rs * g0.x + b0.x);
  o[1] = f2bf((a.y - mu) * rs * g0.y + b0.y);
  o[2] = f2bf((a.z - mu) * rs * g0.z + b0.z);
  o[3] = f2bf((a.w - mu) * rs * g0.w + b0.w);
  o[4] = f2bf((b.x - mu) * rs * g1.x + b1.x);
  o[5] = f2bf((b.y - mu) * rs * g1.y + b1.y);
  o[6] = f2bf((b.z - mu) * rs * g1.z + b1.z);
  o[7] = f2bf((b.w - mu) * rs * g1.w + b1.w);
  *(u16x8*)(y + (size_t)gw * DDIM + l * 8) = o;
}

// ------------- weight convert+transpose: w[K][N] fp32 -> wt[N][K] bf16 ------
__global__ __launch_bounds__(256) void transpose_w(const float* __restrict__ w,
                                                   u16* __restrict__ wt, int K, int N) {
  int idx = blockIdx.x * 256 + threadIdx.x;
  int kb  = K >> 3;
  if (idx >= N * kb) return;
  int n = idx / kb, k0 = (idx - n * kb) * 8;
  u16x8 o;
#pragma unroll
  for (int j = 0; j < 8; ++j) o[j] = f2bf(w[(size_t)(k0 + j) * N + n]);
  *(u16x8*)(wt + (size_t)n * K + k0) = o;
}

// ---------------- GEMM: C[M][N] = A[M][K](bf16) @ Bt[N][K](bf16)^T ----------
// 128x128 tile, BK=32, 4 waves (2x2 of 64x64), global_load_lds staging.
// EPI 0: qkv scatter (bias, q*0.125, head-major bf16 q/k/v)
// EPI 1: fp32 out = acc + bias + res
// EPI 2: bf16 out = gelu(acc + bias)
template <int EPI>
__global__ __launch_bounds__(256) void gemm128(const u16* __restrict__ A,
                                               const u16* __restrict__ Bt,
                                               const float* __restrict__ bias,
                                               const float* __restrict__ res,
                                               float* __restrict__ outf,
                                               u16* __restrict__ outb,
                                               u16* __restrict__ outq,
                                               u16* __restrict__ outk,
                                               u16* __restrict__ outv,
                                               int M, int N, int K) {
  __shared__ u16 As[128 * 32];
  __shared__ u16 Bs[128 * 32];
  const int tid = threadIdx.x;
  const int w = tid >> 6, l = tid & 63;
  const int l15 = l & 15, l4 = l >> 4;
  const int bm = blockIdx.y, bn = blockIdx.x;
  const int wr = w >> 1, wc = w & 1;

  f32x4 acc[4][4] = {};

  // staging: wave w covers rows [w*32, w*32+32); lane l -> row +(l>>2), col (l&3)*8
  const u16* Ag = A  + (size_t)(bm * 128 + w * 32 + (l >> 2)) * K + (l & 3) * 8;
  const u16* Bg = Bt + (size_t)(bn * 128 + w * 32 + (l >> 2)) * K + (l & 3) * 8;
  u16* AsW0 = &As[(w * 2 + 0) * 512];  // wave-uniform LDS bases (1KB chunks)
  u16* AsW1 = &As[(w * 2 + 1) * 512];
  u16* BsW0 = &Bs[(w * 2 + 0) * 512];
  u16* BsW1 = &Bs[(w * 2 + 1) * 512];

  for (int k0 = 0; k0 < K; k0 += 32) {
    gload_lds16(Ag + k0, AsW0);
    gload_lds16(Ag + (size_t)16 * K + k0, AsW1);
    gload_lds16(Bg + k0, BsW0);
    gload_lds16(Bg + (size_t)16 * K + k0, BsW1);
    __syncthreads();
    bf16x8 af[4], bf[4];
#pragma unroll
    for (int m = 0; m < 4; ++m)
      af[m] = *(const bf16x8*)(&As[(wr * 64 + m * 16 + l15) * 32 + l4 * 8]);
#pragma unroll
    for (int n = 0; n < 4; ++n)
      bf[n] = *(const bf16x8*)(&Bs[(wc * 64 + n * 16 + l15) * 32 + l4 * 8]);
#pragma unroll
    for (int m = 0; m < 4; ++m)
#pragma unroll
      for (int n = 0; n < 4; ++n)
        acc[m][n] = __builtin_amdgcn_mfma_f32_16x16x32_bf16(af[m], bf[n], acc[m][n], 0, 0, 0);
    __syncthreads();
  }

#pragma unroll
  for (int m = 0; m < 4; ++m) {
    const int row0 = bm * 128 + wr * 64 + m * 16 + l4 * 4;
#pragma unroll
    for (int n = 0; n < 4; ++n) {
      const int col = bn * 128 + wc * 64 + n * 16 + l15;
      const float bv = bias[col];
#pragma unroll
      for (int r = 0; r < 4; ++r) {
        const int row = row0 + r;
        float val = acc[m][n][r] + bv;
        if constexpr (EPI == 0) {
          int t = col >> 9, hh = (col >> 6) & 7, dk = col & 63;
          u16* dst = (t == 0) ? outq : (t == 1) ? outk : outv;
          if (t == 0) val *= 0.125f;  // fold DK^-0.5 into q
          int bb = row >> 11, cc = row & 2047;
          dst[(((size_t)bb * HH + hh) * CDIM + cc) * DKH + dk] = f2bf(val);
        } else if constexpr (EPI == 1) {
          size_t idx = (size_t)row * N + col;
          outf[idx] = val + res[idx];
        } else {
          float g = 0.5f * val * (1.0f + erff(val * 0.70710678118f));
          outb[(size_t)row * N + col] = f2bf(g);
        }
      }
    }
  }
}

// ---------------- flash attention: block = (b,h, 64-row q tile) -------------
__global__ __launch_bounds__(256) void flash_attn(const u16* __restrict__ Q,
                                                  const u16* __restrict__ K,
                                                  const u16* __restrict__ V,
                                                  const float* __restrict__ adj,
                                                  u16* __restrict__ O) {
  __shared__ u16 Ps[64 * 72];
  __shared__ u16 Vs[64 * 72];  // transposed V tile [dk][k], XOR-granule swizzled
  const int bh = blockIdx.y;
  const int b = bh >> 3, hh = bh & 7;
  const int qt = blockIdx.x;
  const int tid = threadIdx.x;
  const int w = tid >> 6, l = tid & 63;
  const int l15 = l & 15, l4 = l >> 4;
  const u16* Qb = Q + (size_t)bh * CDIM * DKH;
  const u16* Kb = K + (size_t)bh * CDIM * DKH;
  const u16* Vb = V + (size_t)bh * CDIM * DKH;

  bf16x8 qf[2];
  {
    int qrow = qt * 64 + w * 16 + l15;  // A-fragment rows
    qf[0] = *(const bf16x8*)(Qb + (size_t)qrow * DKH + l4 * 8);
    qf[1] = *(const bf16x8*)(Qb + (size_t)qrow * DKH + 32 + l4 * 8);
  }
  float m_run[4], l_run[4];
  f32x4 o_acc[4] = {};
#pragma unroll
  for (int r = 0; r < 4; ++r) { m_run[r] = -1e30f; l_run[r] = 0.f; }
  const int qrow_c = qt * 64 + w * 16 + l4 * 4;  // C-layout rows

  for (int kt = 0; kt < CDIM / 64; ++kt) {
    // stage V transposed: element (dk, k) at Vs[dk*72 + (((k>>3)^(dk>>3))*8 + (k&7))]
#pragma unroll
    for (int rr = 0; rr < 2; ++rr) {
      int k = (tid >> 3) + 32 * rr;
      int dk0 = (tid & 7) * 8;
      u16x8 vv = *(const u16x8*)(Vb + (size_t)(kt * 64 + k) * DKH + dk0);
#pragma unroll
      for (int j = 0; j < 8; ++j) {
        int dk = dk0 + j;
        int g = ((k >> 3) ^ (dk >> 3)) & 7;
        Vs[dk * 72 + g * 8 + (k & 7)] = vv[j];
      }
    }
    // S = Q @ K^T  (K fragments straight from global; L2-resident)
    f32x4 s_acc[4] = {};
#pragma unroll
    for (int s = 0; s < 2; ++s)
#pragma unroll
      for (int f = 0; f < 4; ++f) {
        bf16x8 kf = *(const bf16x8*)(Kb + (size_t)(kt * 64 + f * 16 + l15) * DKH + s * 32 + l4 * 8);
        s_acc[f] = __builtin_amdgcn_mfma_f32_16x16x32_bf16(qf[s], kf, s_acc[f], 0, 0, 0);
      }
    // online softmax (rows live in 16-lane groups; reduce via shfl_xor 1,2,4,8)
    float pv[4][4];
#pragma unroll
    for (int r = 0; r < 4; ++r) {
      const float* adjr = adj + ((size_t)b * CDIM + qrow_c + r) * CDIM + kt * 64 + l15;
      float v0 = s_acc[0][r] + adjr[0];
      float v1 = s_acc[1][r] + adjr[16];
      float v2 = s_acc[2][r] + adjr[32];
      float v3 = s_acc[3][r] + adjr[48];
      float mx = fmaxf(fmaxf(v0, v1), fmaxf(v2, v3));
      mx = fmaxf(mx, __shfl_xor(mx, 1));
      mx = fmaxf(mx, __shfl_xor(mx, 2));
      mx = fmaxf(mx, __shfl_xor(mx, 4));
      mx = fmaxf(mx, __shfl_xor(mx, 8));
      float mnew = fmaxf(m_run[r], mx);
      float fac = expf(m_run[r] - mnew);
      m_run[r] = mnew;
      v0 = expf(v0 - mnew); v1 = expf(v1 - mnew);
      v2 = expf(v2 - mnew); v3 = expf(v3 - mnew);
      pv[0][r] = v0; pv[1][r] = v1; pv[2][r] = v2; pv[3][r] = v3;
      float ss = v0 + v1 + v2 + v3;
      ss += __shfl_xor(ss, 1); ss += __shfl_xor(ss, 2);
      ss += __shfl_xor(ss, 4); ss += __shfl_xor(ss, 8);
      l_run[r] = l_run[r] * fac + ss;
#pragma unroll
      for (int n = 0; n < 4; ++n) o_acc[n][r] *= fac;
    }
    // P -> LDS (bf16), C-layout -> A-layout transpose through LDS
#pragma unroll
    for (int f = 0; f < 4; ++f)
#pragma unroll
      for (int r = 0; r < 4; ++r)
        Ps[(w * 16 + l4 * 4 + r) * 72 + f * 16 + l15] = f2bf(pv[f][r]);
    __syncthreads();
    // O += P @ V
#pragma unroll
    for (int s = 0; s < 2; ++s) {
      bf16x8 pa = *(const bf16x8*)(&Ps[(w * 16 + l15) * 72 + s * 32 + l4 * 8]);
#pragma unroll
      for (int n = 0; n < 4; ++n) {
        int dkr = n * 16 + l15;
        int g = ((s * 4 + l4) ^ (dkr >> 3)) & 7;
        bf16x8 vb = *(const bf16x8*)(&Vs[dkr * 72 + g * 8]);
        o_acc[n] = __builtin_amdgcn_mfma_f32_16x16x32_bf16(pa, vb, o_acc[n], 0, 0, 0);
      }
    }
    __syncthreads();
  }
  // normalize + write attn_out (row-major [8192][512] bf16, col offset hh*64)
#pragma unroll
  for (int r = 0; r < 4; ++r) {
    float inv = 1.0f / l_run[r];
    int orow = qt * 64 + w * 16 + l4 * 4 + r;
    u16* Orow = O + ((size_t)b * CDIM + orow) * DDIM + hh * 64;
#pragma unroll
    for (int n = 0; n < 4; ++n)
      Orow[n * 16 + l15] = f2bf(o_acc[n][r] * inv);
  }
}

extern "C" void kernel_launch(void* const* d_in, const int* in_sizes, int n_in,
                              void* d_out, int out_size, void* d_ws, size_t ws_size,
                              hipStream_t stream) {
  const float* h      = (const float*)d_in[0];
  const float* adj    = (const float*)d_in[1];
  const float* w_qkv  = (const float*)d_in[2];
  const float* b_qkv  = (const float*)d_in[3];
  const float* w_out  = (const float*)d_in[4];
  const float* b_out  = (const float*)d_in[5];
  const float* ln1g   = (const float*)d_in[6];
  const float* ln1b   = (const float*)d_in[7];
  const float* ln2g   = (const float*)d_in[8];
  const float* ln2b   = (const float*)d_in[9];
  const float* w1     = (const float*)d_in[10];
  const float* b1     = (const float*)d_in[11];
  const float* w2     = (const float*)d_in[12];
  const float* b2     = (const float*)d_in[13];
  float* out = (float*)d_out;

  char* ws = (char*)d_ws;
  const size_t SZ = (size_t)NROW * DDIM * 2;  // 8 MB (bf16 8192x512)
  u16* hn    = (u16*)(ws);                    // h_n bf16; later reused as ff_in
  u16* qb    = (u16*)(ws + SZ);               // q head-major; later ff_mid spans q..k
  u16* kb    = (u16*)(ws + 2 * SZ);
  u16* vb    = (u16*)(ws + 3 * SZ);
  u16* attn  = (u16*)(ws + 4 * SZ);
  u16* wqkvt = (u16*)(ws + 5 * SZ);                       // 1536x512 bf16 = 1.5MB
  u16* woutt = (u16*)(ws + 5 * SZ + 1572864);             // 512x512
  u16* w1t   = (u16*)(ws + 5 * SZ + 1572864 + 524288);    // 1024x512
  u16* w2t   = (u16*)(ws + 5 * SZ + 1572864 + 524288 + 1048576);  // 512x1024
  u16* ffin  = hn;
  u16* ffmid = qb;  // 16MB spans q+k (both dead after flash_attn)

  transpose_w<<<384, 256, 0, stream>>>(w_qkv, wqkvt, 512, 1536);
  transpose_w<<<128, 256, 0, stream>>>(w_out, woutt, 512, 512);
  transpose_w<<<256, 256, 0, stream>>>(w1, w1t, 512, 1024);
  transpose_w<<<256, 256, 0, stream>>>(w2, w2t, 1024, 512);

  ln_kernel<<<2048, 256, 0, stream>>>(h, ln1g, ln1b, hn, NROW);

  gemm128<0><<<dim3(12, 64), 256, 0, stream>>>(hn, wqkvt, b_qkv, nullptr,
                                               nullptr, nullptr, qb, kb, vb,
                                               NROW, 3 * DDIM, DDIM);

  flash_attn<<<dim3(32, 32), 256, 0, stream>>>(qb, kb, vb, adj, attn);

  gemm128<1><<<dim3(4, 64), 256, 0, stream>>>(attn, woutt, b_out, h,
                                              out, nullptr, nullptr, nullptr, nullptr,
                                              NROW, DDIM, DDIM);

  ln_kernel<<<2048, 256, 0, stream>>>(out, ln2g, ln2b, ffin, NROW);

  gemm128<2><<<dim3(8, 64), 256, 0, stream>>>(ffin, w1t, b1, nullptr,
                                              nullptr, ffmid, nullptr, nullptr, nullptr,
                                              NROW, 2 * DDIM, DDIM);

  gemm128<1><<<dim3(4, 64), 256, 0, stream>>>(ffmid, w2t, b2, out,
                                              out, nullptr, nullptr, nullptr, nullptr,
                                              NROW, DDIM, 2 * DDIM);
}